// Round 1
// baseline (353.284 us; speedup 1.0000x reference)
//
#include <hip/hip_runtime.h>

// Multi-class hinge (Crammer-Singer) loss, summed over batch.
// outputs: [N=16384, C=4096] fp32, labels: [N] int32, result: scalar fp32 sum.
// Memory-bound: 256 MiB single-pass read -> roofline ~43 us @ 6.3 TB/s.

#define N_ROWS 16384
#define C_COLS 4096
#define BLOCK  256
#define GRID   2048   // 8 rows per block via grid-stride

__global__ __launch_bounds__(BLOCK) void hinge_sum_kernel(
    const float* __restrict__ outs,
    const int*   __restrict__ labels,
    float*       __restrict__ result)
{
    const int tid = threadIdx.x;
    float acc = 0.0f;
    int rows_done = 0;

    for (int row = blockIdx.x; row < N_ROWS; row += GRID) {
        const float* rp  = outs + (size_t)row * C_COLS;
        const int    lbl = labels[row];        // broadcast (same addr all lanes)
        const float  gm1 = 1.0f - rp[lbl];     // broadcast load of ground
        const float4* rp4 = (const float4*)rp; // row is 16KiB-aligned, C%4==0

        // 1024 float4 per row / 256 threads = 4 float4 per thread, coalesced
        #pragma unroll
        for (int k = 0; k < 4; ++k) {
            float4 v = rp4[tid + k * BLOCK];
            acc += fmaxf(v.x + gm1, 0.0f);
            acc += fmaxf(v.y + gm1, 0.0f);
            acc += fmaxf(v.z + gm1, 0.0f);
            acc += fmaxf(v.w + gm1, 0.0f);
        }
        ++rows_done;  // uniform across the block
    }

    // wave (64-lane) shuffle reduction
    #pragma unroll
    for (int off = 32; off > 0; off >>= 1)
        acc += __shfl_down(acc, off, 64);

    __shared__ float wave_sums[BLOCK / 64];
    const int wave = tid >> 6;
    if ((tid & 63) == 0) wave_sums[wave] = acc;
    __syncthreads();

    if (tid == 0) {
        float s = wave_sums[0] + wave_sums[1] + wave_sums[2] + wave_sums[3];
        // j == label contributes exactly max(0 + 1, 0) = 1.0 per row; reference
        // excludes it -> subtract 1.0 per processed row.
        s -= (float)rows_done;
        atomicAdd(result, s);
    }
}

extern "C" void kernel_launch(void* const* d_in, const int* in_sizes, int n_in,
                              void* d_out, int out_size, void* d_ws, size_t ws_size,
                              hipStream_t stream) {
    const float* outs   = (const float*)d_in[0];
    const int*   labels = (const int*)d_in[1];
    float*       result = (float*)d_out;

    // d_out is poisoned to 0xAA before every timed launch -> zero it first.
    hipMemsetAsync(result, 0, sizeof(float), stream);
    hinge_sum_kernel<<<GRID, BLOCK, 0, stream>>>(outs, labels, result);
}

// Round 2
// 352.486 us; speedup vs baseline: 1.0023x; 1.0023x over previous
//
#include <hip/hip_runtime.h>

// Multi-class hinge (Crammer-Singer) loss, summed over batch.
// outputs: [N=16384, C=4096] fp32, labels: [N] int32, result: scalar fp32 sum.
// Memory-bound: 256 MiB single-pass read -> roofline ~43 us @ 6.3 TB/s.
//
// R2: atomicAdd(1 addr) -> per-block partials in d_ws + tiny reduce kernel
//     (2048 same-address atomics serialize at L2; partials are contention-free
//      and deterministic). Ground-value loads software-pipelined one row ahead
//     (labels[row] -> outs[row][lbl] is a 2-deep dependent chain, ~1.8k cyc).

#define N_ROWS 16384
#define C_COLS 4096
#define BLOCK  256
#define GRID   2048
#define ROWS_PER_BLOCK (N_ROWS / GRID)   // 8

__global__ __launch_bounds__(BLOCK) void hinge_partial_kernel(
    const float* __restrict__ outs,
    const int*   __restrict__ labels,
    float*       __restrict__ partials)
{
    const int tid = threadIdx.x;
    float acc = 0.0f;

    int row = blockIdx.x;
    // Prefetch first row's label + ground (dependent chain issued early).
    int   lbl = labels[row];
    float g   = outs[(size_t)row * C_COLS + lbl];

    #pragma unroll
    for (int i = 0; i < ROWS_PER_BLOCK; ++i) {
        const float4* rp4 = (const float4*)(outs + (size_t)row * C_COLS);
        const float gm1 = 1.0f - g;

        // Software-pipeline: issue next row's label->ground chain now, so its
        // ~1.8k-cycle latency overlaps this row's accumulation.
        const int nrow = row + GRID;
        if (i + 1 < ROWS_PER_BLOCK) {
            int nlbl = labels[nrow];
            g = outs[(size_t)nrow * C_COLS + nlbl];
        }

        // 1024 float4 per row / 256 threads = 4 float4/thread, coalesced 16B.
        #pragma unroll
        for (int k = 0; k < 4; ++k) {
            float4 v = rp4[tid + k * BLOCK];
            acc += fmaxf(v.x + gm1, 0.0f);
            acc += fmaxf(v.y + gm1, 0.0f);
            acc += fmaxf(v.z + gm1, 0.0f);
            acc += fmaxf(v.w + gm1, 0.0f);
        }
        row = nrow;
    }

    // wave (64-lane) shuffle reduction
    #pragma unroll
    for (int off = 32; off > 0; off >>= 1)
        acc += __shfl_down(acc, off, 64);

    __shared__ float wave_sums[BLOCK / 64];
    const int wave = tid >> 6;
    if ((tid & 63) == 0) wave_sums[wave] = acc;
    __syncthreads();

    if (tid == 0)
        partials[blockIdx.x] = wave_sums[0] + wave_sums[1] +
                               wave_sums[2] + wave_sums[3];
}

__global__ __launch_bounds__(BLOCK) void hinge_reduce_kernel(
    const float* __restrict__ partials,
    float*       __restrict__ result)
{
    const int tid = threadIdx.x;
    float acc = 0.0f;
    #pragma unroll
    for (int i = 0; i < GRID / BLOCK; ++i)     // 8 partials per thread
        acc += partials[tid + i * BLOCK];

    #pragma unroll
    for (int off = 32; off > 0; off >>= 1)
        acc += __shfl_down(acc, off, 64);

    __shared__ float wave_sums[BLOCK / 64];
    const int wave = tid >> 6;
    if ((tid & 63) == 0) wave_sums[wave] = acc;
    __syncthreads();

    if (tid == 0) {
        float s = wave_sums[0] + wave_sums[1] + wave_sums[2] + wave_sums[3];
        // j == label contributes exactly max(0+1,0)=1.0 per row; the reference
        // masks it out -> subtract 1.0 per row.
        result[0] = s - (float)N_ROWS;
    }
}

extern "C" void kernel_launch(void* const* d_in, const int* in_sizes, int n_in,
                              void* d_out, int out_size, void* d_ws, size_t ws_size,
                              hipStream_t stream) {
    const float* outs     = (const float*)d_in[0];
    const int*   labels   = (const int*)d_in[1];
    float*       result   = (float*)d_out;
    float*       partials = (float*)d_ws;      // 2048 floats = 8 KB scratch

    hinge_partial_kernel<<<GRID, BLOCK, 0, stream>>>(outs, labels, partials);
    hinge_reduce_kernel<<<1, BLOCK, 0, stream>>>(partials, result);
}